// Round 5
// baseline (95.278 us; speedup 1.0000x reference)
//
#include <hip/hip_runtime.h>
#include <hip/hip_fp16.h>
#include <math.h>

// Problem constants (match reference)
#define NCURVES   256
#define GPER      64               // NUM_BEZIERS * NUM_SAMPLES = 2*32
#define NUM_G     (NCURVES*GPER)   // 16384
#define IMG_W     256
#define IMG_H     256
#define TILE      8                // 8x8 tile = exactly one wave (64 px)
#define TILES_X   (IMG_W/TILE)     // 32
#define TILES_Y   (IMG_H/TILE)     // 32
#define NTILES    (TILES_X*TILES_Y) // 1024
#define REC_F     8                // floats per gaussian record (32 B: 2 float4)

#define A_MIN     3.0e-6f          // alpha cutoff for tile bbox
#define P_CUT     (-12.6f)         // per-pixel power cutoff (consistent with A_MIN)
#define T_EPS     1.0e-5f          // transmittance early-out (residual <= 1e-5)

#define WQ        4                // depth-quarter waves per block
#define GQ        (NUM_G/WQ)       // 4096 sorted gaussians per wave

// ---------------------------------------------------------------------------
// Kernel 1 (prep): verified math, unchanged except bbox at TILE=8 granularity.
// 256 blocks x 64 threads. record: {mx,my,A,B},{C,alpha,rg(f16x2),cb(f16)}.
// ---------------------------------------------------------------------------
__global__ __launch_bounds__(GPER)
void prep(const float* __restrict__ ctrl,        // [256][10][2]
          const float* __restrict__ features,    // [256][3]
          const float* __restrict__ cholesky,    // [256][3]
          const float* __restrict__ opacity,     // [256]
          const float* __restrict__ depth,       // [256]
          float*       __restrict__ recs,        // [NUM_G][8]
          unsigned*    __restrict__ bbox)        // [NUM_G]
{
    int c   = blockIdx.x;
    int tid = threadIdx.x;          // 0..63 (exactly one wave)

    // ---- stable rank (matches stable argsort over 64x-repeated depths)
    float dc = depth[c];
    int r = 0;
    #pragma unroll
    for (int jj = 0; jj < 4; ++jj) {
        int j = tid + jj*64;
        float dj = depth[j];
        r += (dj < dc) || (dj == dc && j < c);
    }
    #pragma unroll
    for (int off = 32; off > 0; off >>= 1) r += __shfl_down(r, off, 64);
    r = __shfl(r, 0, 64);

    // ---- per-curve params
    float c0 = cholesky[3*c+0] + 0.5f;
    float c1 = cholesky[3*c+1];
    float c2 = cholesky[3*c+2] + 0.5f;
    float s00 = c0*c0;
    float s01 = c0*c1;
    float s11 = c1*c1 + c2*c2;
    float inv = 1.0f / (s00*s11 - s01*s01);
    float A  =  s11*inv;
    float Bc = -s01*inv;
    float Cc =  s00*inv;

    float cr = 1.0f/(1.0f + __expf(-features[3*c+0]));
    float cg = 1.0f/(1.0f + __expf(-features[3*c+1]));
    float cb = 1.0f/(1.0f + __expf(-features[3*c+2]));
    float al = 1.0f/(1.0f + __expf(-opacity[c]));

    float cut = fmaxf(2.0f*(__logf(al) - __logf(A_MIN)), 0.0f);
    float rx = sqrtf(cut * s00);
    float ry = sqrtf(cut * s11);

    // ---- bezier sample -> mean
    int k = tid >> 5;               // bezier segment 0/1
    int s = tid & 31;               // sample 0..31
    float t = 0.007f + (float)s * (0.986f/31.0f);
    float u = 1.0f - t;
    float t2=t*t, t3=t2*t, t4=t3*t, t5=t4*t;
    float u2=u*u, u3=u2*u, u4=u3*u, u5=u4*u;
    float w[6] = { u5, 5.0f*t*u4, 10.0f*t2*u3, 10.0f*t3*u2, 5.0f*t4*u, t5 };

    const float* cp = ctrl + c*20;
    float px = 0.0f, py = 0.0f;
    #pragma unroll
    for (int j = 0; j < 6; ++j) {
        int idx = (k*5 + j) % 10;   // seg0: 0..5 ; seg1: 5,6,7,8,9,0
        px += w[j]*cp[2*idx+0];
        py += w[j]*cp[2*idx+1];
    }
    float mx = (tanhf(px)*0.5f + 0.5f) * (float)IMG_W;
    float my = (tanhf(py)*0.5f + 0.5f) * (float)IMG_H;

    int gi = r*GPER + tid;          // depth-sorted gaussian index (stable ties)

    unsigned rg  = (unsigned)__half_as_ushort(__float2half_rn(cr))
                 | ((unsigned)__half_as_ushort(__float2half_rn(cg)) << 16);
    unsigned cbp = (unsigned)__half_as_ushort(__float2half_rn(cb));

    float4* o4 = (float4*)(recs + (size_t)gi*REC_F);
    o4[0] = make_float4(mx, my, A, Bc);
    o4[1] = make_float4(Cc, al, __uint_as_float(rg), __uint_as_float(cbp));

    int tx0 = min(max((int)floorf((mx - rx) * (1.0f/TILE)), 0), TILES_X-1);
    int tx1 = min(max((int)floorf((mx + rx) * (1.0f/TILE)), 0), TILES_X-1);
    int ty0 = min(max((int)floorf((my - ry) * (1.0f/TILE)), 0), TILES_Y-1);
    int ty1 = min(max((int)floorf((my + ry) * (1.0f/TILE)), 0), TILES_Y-1);
    bbox[gi] = (unsigned)tx0 | ((unsigned)ty0<<8) | ((unsigned)tx1<<16) | ((unsigned)ty1<<24);
}

// ---------------------------------------------------------------------------
// Kernel 2 (render8x8): 1024 blocks (one per 8x8 tile) x 256 threads
// (4 waves = 4 depth-quarters). Replaces render + combine + partial buffer.
//
// Wave w (ZERO barriers, fully wave-private):
//   - scans sorted-gi range [w*4096,(w+1)*4096) (64 bbox tests/lane),
//     ballot-compacting hits into its own LDS list (capacity = full range,
//     overflow impossible);
//   - composites its ordered list for its 64 pixels (1 px/lane) straight
//     from L2 (records wave-broadcast), with wave-local T early-out
//     (residual < T_EPS, same bound as prior rounds).
// Then ONE barrier, and wave 0 combines the 4 depth partials in order
// (associative compositing), adds background, clamps, stores final pixels.
//
// Load balance: the hot 16x16 tile's work is now 4 smaller 8x8 tiles on 4
// different CUs, each split over 4 SIMDs -> worst block ~3 us (vs R2's 26).
// Occupancy: LDS 36 KB -> 4 blocks/CU -> all 1024 blocks resident, 4
// waves/SIMD TLP hides the L2 dependent chain (R3's latency lesson).
// ---------------------------------------------------------------------------
__global__ __launch_bounds__(256)
void render8x8(const float*    __restrict__ recs,
               const unsigned* __restrict__ bbox,
               const float*    __restrict__ background,
               float*          __restrict__ out)
{
    __shared__ unsigned short lst[WQ][GQ];   // 32 KB: per-wave ordered hit lists
    __shared__ float4         pc[WQ][64];    //  4 KB: per-wave pixel partials

    int tid   = threadIdx.x;
    int lane  = tid & 63;
    int w     = tid >> 6;                    // depth quarter 0..3
    int tile  = blockIdx.x;                  // 0..1023
    int tilex = tile & (TILES_X-1);
    int tiley = tile >> 5;
    unsigned long long lmask = (1ull << lane) - 1ull;

    int gb = w * GQ;                         // this wave's sorted-gi base

    // ---- scan: 64 bbox tests per lane, 8 batches of 8 prefetched loads
    int cnt = 0;
    #pragma unroll 1
    for (int b = 0; b < 8; ++b) {
        unsigned bb[8];
        #pragma unroll
        for (int u = 0; u < 8; ++u)
            bb[u] = bbox[gb + (b*8 + u)*64 + lane];
        #pragma unroll
        for (int u = 0; u < 8; ++u) {
            unsigned v = bb[u];
            bool pred = (tilex >= (int)( v        & 0xff)) &
                        (tilex <= (int)((v >> 16) & 0xff)) &
                        (tiley >= (int)((v >>  8) & 0xff)) &
                        (tiley <= (int)((v >> 24) & 0xff));
            unsigned long long m = __ballot(pred ? 1 : 0);
            if (pred)
                lst[w][cnt + (int)__popcll(m & lmask)] =
                    (unsigned short)((b*8 + u)*64 + lane);
            cnt += (int)__popcll(m);
        }
    }

    // ---- composite this wave's ordered quarter for its 64 pixels
    float pxf = (float)(tilex*TILE + (lane & 7)) + 0.5f;
    float pyf = (float)(tiley*TILE + (lane >> 3)) + 0.5f;

    float T = 1.0f, accr = 0.0f, accg = 0.0f, accb = 0.0f;

    #pragma unroll 2
    for (int j = 0; j < cnt; ++j) {
        int g = gb + (int)lst[w][j];                    // LDS broadcast
        const float4* rp = (const float4*)(recs + (size_t)g*REC_F);
        float4 r0 = rp[0];          // mx, my, A, B   (wave-broadcast, L2)
        float4 r1 = rp[1];          // C, alpha, rg(f16x2), cb(f16)
        float dx = pxf - r0.x;
        float dy = pyf - r0.y;
        float p  = -0.5f*(r0.z*dx*dx + r1.x*dy*dy) - r0.w*dx*dy;
        if (p > P_CUT) {
            float a = fminf(r1.y * __expf(p), 0.999f);
            float wgt = a * T;
            unsigned rg = __float_as_uint(r1.z);
            accr += wgt * __half2float(__ushort_as_half((unsigned short)(rg & 0xffff)));
            accg += wgt * __half2float(__ushort_as_half((unsigned short)(rg >> 16)));
            accb += wgt * __half2float(__ushort_as_half((unsigned short)__float_as_uint(r1.w)));
            T *= (1.0f - a);
        }
        if (!__any(T > T_EPS)) break;   // wave-uniform; residual < T_EPS
    }

    pc[w][lane] = make_float4(accr, accg, accb, T);
    __syncthreads();                     // the block's ONLY barrier

    // ---- wave 0: combine 4 depth-ordered partials, + background, store
    if (w == 0) {
        float4 a0 = pc[0][lane];
        float4 a1 = pc[1][lane];
        float4 a2 = pc[2][lane];
        float4 a3 = pc[3][lane];
        float r = a0.x + a0.w*(a1.x + a1.w*(a2.x + a2.w*a3.x));
        float g = a0.y + a0.w*(a1.y + a1.w*(a2.y + a2.w*a3.y));
        float b = a0.z + a0.w*(a1.z + a1.w*(a2.z + a2.w*a3.z));
        float Tt = a0.w * a1.w * a2.w * a3.w;

        r = fminf(fmaxf(r + Tt*background[0], 0.0f), 1.0f);
        g = fminf(fmaxf(g + Tt*background[1], 0.0f), 1.0f);
        b = fminf(fmaxf(b + Tt*background[2], 0.0f), 1.0f);

        int X = tilex*TILE + (lane & 7);
        int Y = tiley*TILE + (lane >> 3);
        size_t oi = ((size_t)Y*IMG_W + X)*3;
        out[oi+0] = r;
        out[oi+1] = g;
        out[oi+2] = b;
    }
}

// ---------------------------------------------------------------------------
extern "C" void kernel_launch(void* const* d_in, const int* in_sizes, int n_in,
                              void* d_out, int out_size, void* d_ws, size_t ws_size,
                              hipStream_t stream)
{
    const float* ctrl       = (const float*)d_in[0];  // (256,10,2)
    const float* features   = (const float*)d_in[1];  // (256,3)
    const float* cholesky   = (const float*)d_in[2];  // (256,3)
    const float* opacity    = (const float*)d_in[3];  // (256,1)
    const float* depth      = (const float*)d_in[4];  // (256,1)
    const float* background = (const float*)d_in[5];  // (3,)
    float* out = (float*)d_out;                       // (256,256,3)

    // workspace layout (16B-aligned); partial buffer + combine kernel removed
    char* w = (char*)d_ws;
    float*    recs  = (float*)   (w);                 // 524288 B
    unsigned* bboxp = (unsigned*)(w + 524288);        //  65536 B

    prep<<<NCURVES, GPER, 0, stream>>>(ctrl, features, cholesky, opacity, depth,
                                       recs, bboxp);
    render8x8<<<NTILES, 256, 0, stream>>>(recs, bboxp, background, out);
}

// Round 6
// 83.140 us; speedup vs baseline: 1.1460x; 1.1460x over previous
//
#include <hip/hip_runtime.h>
#include <hip/hip_fp16.h>
#include <math.h>

// Problem constants (match reference)
#define NCURVES   256
#define GPER      64               // NUM_BEZIERS * NUM_SAMPLES = 2*32
#define NUM_G     (NCURVES*GPER)   // 16384
#define IMG_W     256
#define IMG_H     256
#define TILE      16
#define TILES_X   (IMG_W/TILE)     // 16
#define TILES_Y   (IMG_H/TILE)     // 16
#define NTILES    (TILES_X*TILES_Y) // 256
#define REC_F     8                // floats per gaussian record (32 B: 2 float4)

#define A_MIN     3.0e-6f          // alpha cutoff for tile bbox
#define P_CUT     (-12.6f)         // per-pixel power cutoff (consistent with A_MIN)
#define T_EPS     1.0e-5f          // transmittance early-out (residual <= 1e-5)

#define SEGS      8                // depth slices (by gi range) -> cross-CU split
#define GSEG      (NUM_G/SEGS)     // 2048 gaussians per slice
#define GWAVE     (GSEG/4)         // 512 per scan wave (4 waves/block)
#define STAGE     512              // staged records per chunk (16 KB LDS)

// ---------------------------------------------------------------------------
// Kernel 1 (prep): UNCHANGED (verified R3/R4). 256 blocks x 64 threads.
// record: {mx,my,A,B},{C,alpha,rg(f16x2),cb(f16)}.
// ---------------------------------------------------------------------------
__global__ __launch_bounds__(GPER)
void prep(const float* __restrict__ ctrl,        // [256][10][2]
          const float* __restrict__ features,    // [256][3]
          const float* __restrict__ cholesky,    // [256][3]
          const float* __restrict__ opacity,     // [256]
          const float* __restrict__ depth,       // [256]
          float*       __restrict__ recs,        // [NUM_G][8]
          unsigned*    __restrict__ bbox)        // [NUM_G]
{
    int c   = blockIdx.x;
    int tid = threadIdx.x;          // 0..63 (exactly one wave)

    // ---- stable rank (matches stable argsort over 64x-repeated depths)
    float dc = depth[c];
    int r = 0;
    #pragma unroll
    for (int jj = 0; jj < 4; ++jj) {
        int j = tid + jj*64;
        float dj = depth[j];
        r += (dj < dc) || (dj == dc && j < c);
    }
    #pragma unroll
    for (int off = 32; off > 0; off >>= 1) r += __shfl_down(r, off, 64);
    r = __shfl(r, 0, 64);

    // ---- per-curve params
    float c0 = cholesky[3*c+0] + 0.5f;
    float c1 = cholesky[3*c+1];
    float c2 = cholesky[3*c+2] + 0.5f;
    float s00 = c0*c0;
    float s01 = c0*c1;
    float s11 = c1*c1 + c2*c2;
    float inv = 1.0f / (s00*s11 - s01*s01);
    float A  =  s11*inv;
    float Bc = -s01*inv;
    float Cc =  s00*inv;

    float cr = 1.0f/(1.0f + __expf(-features[3*c+0]));
    float cg = 1.0f/(1.0f + __expf(-features[3*c+1]));
    float cb = 1.0f/(1.0f + __expf(-features[3*c+2]));
    float al = 1.0f/(1.0f + __expf(-opacity[c]));

    float cut = fmaxf(2.0f*(__logf(al) - __logf(A_MIN)), 0.0f);
    float rx = sqrtf(cut * s00);
    float ry = sqrtf(cut * s11);

    // ---- bezier sample -> mean
    int k = tid >> 5;               // bezier segment 0/1
    int s = tid & 31;               // sample 0..31
    float t = 0.007f + (float)s * (0.986f/31.0f);
    float u = 1.0f - t;
    float t2=t*t, t3=t2*t, t4=t3*t, t5=t4*t;
    float u2=u*u, u3=u2*u, u4=u3*u, u5=u4*u;
    float w[6] = { u5, 5.0f*t*u4, 10.0f*t2*u3, 10.0f*t3*u2, 5.0f*t4*u, t5 };

    const float* cp = ctrl + c*20;
    float px = 0.0f, py = 0.0f;
    #pragma unroll
    for (int j = 0; j < 6; ++j) {
        int idx = (k*5 + j) % 10;   // seg0: 0..5 ; seg1: 5,6,7,8,9,0
        px += w[j]*cp[2*idx+0];
        py += w[j]*cp[2*idx+1];
    }
    float mx = (tanhf(px)*0.5f + 0.5f) * (float)IMG_W;
    float my = (tanhf(py)*0.5f + 0.5f) * (float)IMG_H;

    int gi = r*GPER + tid;          // depth-sorted gaussian index (stable ties)

    unsigned rg  = (unsigned)__half_as_ushort(__float2half_rn(cr))
                 | ((unsigned)__half_as_ushort(__float2half_rn(cg)) << 16);
    unsigned cbp = (unsigned)__half_as_ushort(__float2half_rn(cb));

    float4* o4 = (float4*)(recs + (size_t)gi*REC_F);
    o4[0] = make_float4(mx, my, A, Bc);
    o4[1] = make_float4(Cc, al, __uint_as_float(rg), __uint_as_float(cbp));

    int tx0 = min(max((int)floorf((mx - rx) * (1.0f/TILE)), 0), TILES_X-1);
    int tx1 = min(max((int)floorf((mx + rx) * (1.0f/TILE)), 0), TILES_X-1);
    int ty0 = min(max((int)floorf((my - ry) * (1.0f/TILE)), 0), TILES_Y-1);
    int ty1 = min(max((int)floorf((my + ry) * (1.0f/TILE)), 0), TILES_Y-1);
    bbox[gi] = (unsigned)tx0 | ((unsigned)ty0<<8) | ((unsigned)tx1<<16) | ((unsigned)ty1<<24);
}

// ---------------------------------------------------------------------------
// Kernel 2 (render8): R3 structure (grid = (tile, gi-eighth) = 2048 x 256,
// balanced cross-CU depth split). Round-6 change is ONLY the composite
// memory path:
//  - R3 read records from L2 inside the loop: ~160 cyc/iter dependent chain,
//    latency-exposed in the occupancy tail -> ~14 us.
//  - R5's per-iter __any break serialized it further (lesson: wave votes
//    between iterations kill pipelining).
//  - Now: cooperatively STAGE the compacted records into LDS (independent
//    32B loads, throughput-bound; one chunk for any realistic block), then
//    composite from LDS with unroll-4 and an early-out checked only at
//    32-iteration boundaries (outside the unrolled body).
// LDS 20.3 KB -> 7 blocks/CU.
// ---------------------------------------------------------------------------
__global__ __launch_bounds__(256)
void render8(const float*    __restrict__ recs,
             const unsigned* __restrict__ bbox,
             float4*         __restrict__ partial)   // [SEGS][IMG_H*IMG_W]
{
    __shared__ unsigned short flat[GSEG];   // 4 KB: ordered hit list (gi-local)
    __shared__ float4         sd[STAGE][2]; // 16 KB: staged records
    __shared__ unsigned       wn[4];

    int tid   = threadIdx.x;
    int seg   = blockIdx.x & (SEGS-1);
    int tile  = blockIdx.x >> 3;            // 0..255
    int tilex = tile & (TILES_X-1);
    int tiley = tile >> 4;

    int lane = tid & 63;
    int wid  = tid >> 6;                    // 0..3
    unsigned long long lmask = (1ull << lane) - 1ull;

    int sbase = seg * GSEG;
    int gwave = wid * GWAVE;                // local base of this wave's subrange

    // ---- Phase 1a: predicate + count (verified R3)
    bool pr[8];
    int cnt = 0;
    {
        unsigned bb[8];
        #pragma unroll
        for (int u = 0; u < 8; ++u)
            bb[u] = bbox[sbase + gwave + u*64 + lane];
        #pragma unroll
        for (int u = 0; u < 8; ++u) {
            unsigned b = bb[u];
            pr[u] = (tilex >= (int)( b        & 0xff)) &
                    (tilex <= (int)((b >> 16) & 0xff)) &
                    (tiley >= (int)((b >>  8) & 0xff)) &
                    (tiley <= (int)((b >> 24) & 0xff));
            cnt += (int)__popcll(__ballot(pr[u] ? 1 : 0));
        }
    }
    if (lane == 0) wn[wid] = (unsigned)cnt;
    __syncthreads();

    unsigned p1 = wn[0], p2 = p1 + wn[1], p3 = p2 + wn[2];
    int total = (int)(p3 + wn[3]);

    // ---- Phase 1b: compact into flat ordered list (verified R3)
    if (total) {
        unsigned base = (wid == 0) ? 0u : (wid == 1) ? p1 : (wid == 2) ? p2 : p3;
        int off = 0;
        #pragma unroll
        for (int u = 0; u < 8; ++u) {
            unsigned long long m = __ballot(pr[u] ? 1 : 0);
            if (pr[u])
                flat[base + off + (int)__popcll(m & lmask)] =
                    (unsigned short)(gwave + u*64 + lane);
            off += (int)__popcll(m);
        }
    }
    __syncthreads();

    // ---- Phase 2: LDS-staged composite
    int ix = tid & (TILE-1);
    int iy = tid >> 4;
    float pxf = (float)(tilex*TILE + ix) + 0.5f;
    float pyf = (float)(tiley*TILE + iy) + 0.5f;

    float T = 1.0f, accr = 0.0f, accg = 0.0f, accb = 0.0f;

    #pragma unroll 1
    for (int base = 0; base < total; base += STAGE) {
        // block-wide early-out doubles as the pre-stage barrier
        int nalive = __syncthreads_count(T > T_EPS);
        if (nalive == 0) break;                     // uniform

        int nstage = total - base;
        if (nstage > STAGE) nstage = STAGE;

        // stage: independent scattered 32B loads, throughput-bound
        for (int e = tid; e < nstage; e += 256) {
            int g = sbase + (int)flat[base + e];
            const float4* rp = (const float4*)(recs + (size_t)g*REC_F);
            sd[e][0] = rp[0];
            sd[e][1] = rp[1];
        }
        __syncthreads();                            // sd[] visible

        // composite from LDS; early-out only at 32-iter boundaries so the
        // unrolled body stays vote-free and pipelineable
        #pragma unroll 1
        for (int jb = 0; jb < nstage; jb += 32) {
            if (!__any(T > T_EPS)) break;           // wave-uniform
            int je = jb + 32 < nstage ? jb + 32 : nstage;
            #pragma unroll 4
            for (int j = jb; j < je; ++j) {
                float4 r0 = sd[j][0];       // mx, my, A, B   (broadcast)
                float4 r1 = sd[j][1];       // C, alpha, rg(f16x2), cb(f16)
                float dx = pxf - r0.x;
                float dy = pyf - r0.y;
                float p  = -0.5f*(r0.z*dx*dx + r1.x*dy*dy) - r0.w*dx*dy;
                if (p > P_CUT) {
                    float a = fminf(r1.y * __expf(p), 0.999f);
                    float wgt = a * T;
                    unsigned rg = __float_as_uint(r1.z);
                    accr += wgt * __half2float(__ushort_as_half((unsigned short)(rg & 0xffff)));
                    accg += wgt * __half2float(__ushort_as_half((unsigned short)(rg >> 16)));
                    accb += wgt * __half2float(__ushort_as_half((unsigned short)__float_as_uint(r1.w)));
                    T *= (1.0f - a);
                }
            }
        }
        __syncthreads();                            // protect sd[] reuse
    }

    int X = tilex*TILE + ix;
    int Y = tiley*TILE + iy;
    partial[(size_t)seg*(IMG_W*IMG_H) + (size_t)Y*IMG_W + X] =
        make_float4(accr, accg, accb, T);
}

// ---------------------------------------------------------------------------
// Kernel 3: combine the 8 depth-ordered slices front-to-back, + background,
// clamp, store. UNCHANGED (verified R3).
// ---------------------------------------------------------------------------
__global__ __launch_bounds__(256)
void combine(const float4* __restrict__ partial,
             const float*  __restrict__ background,
             float*        __restrict__ out)
{
    int p = blockIdx.x * 256 + threadIdx.x;     // pixel 0..65535

    float accr = 0.0f, accg = 0.0f, accb = 0.0f, T = 1.0f;
    #pragma unroll
    for (int s = 0; s < SEGS; ++s) {
        float4 q = partial[(size_t)s*(IMG_W*IMG_H) + p];
        accr += T * q.x;
        accg += T * q.y;
        accb += T * q.z;
        T    *= q.w;
    }
    float r = fminf(fmaxf(accr + T*background[0], 0.0f), 1.0f);
    float g = fminf(fmaxf(accg + T*background[1], 0.0f), 1.0f);
    float b = fminf(fmaxf(accb + T*background[2], 0.0f), 1.0f);

    size_t oi = (size_t)p*3;
    out[oi+0] = r;
    out[oi+1] = g;
    out[oi+2] = b;
}

// ---------------------------------------------------------------------------
extern "C" void kernel_launch(void* const* d_in, const int* in_sizes, int n_in,
                              void* d_out, int out_size, void* d_ws, size_t ws_size,
                              hipStream_t stream)
{
    const float* ctrl       = (const float*)d_in[0];  // (256,10,2)
    const float* features   = (const float*)d_in[1];  // (256,3)
    const float* cholesky   = (const float*)d_in[2];  // (256,3)
    const float* opacity    = (const float*)d_in[3];  // (256,1)
    const float* depth      = (const float*)d_in[4];  // (256,1)
    const float* background = (const float*)d_in[5];  // (3,)
    float* out = (float*)d_out;                       // (256,256,3)

    // workspace layout (16B-aligned)
    char* w = (char*)d_ws;
    float*    recs    = (float*)   (w);                    // 524288 B
    unsigned* bboxp   = (unsigned*)(w + 524288);           //  65536 B
    float4*   partial = (float4*)  (w + 524288 + 65536);   // 8 MiB

    prep<<<NCURVES, GPER, 0, stream>>>(ctrl, features, cholesky, opacity, depth,
                                       recs, bboxp);
    render8<<<NTILES*SEGS, 256, 0, stream>>>(recs, bboxp, partial);
    combine<<<(IMG_W*IMG_H)/256, 256, 0, stream>>>(partial, background, out);
}